// Round 1
// baseline (463.740 us; speedup 1.0000x reference)
//
#include <hip/hip_runtime.h>
#include <math.h>

// Problem: bs=8, seq=2048, d_in=d_out=2048, R=8, ctr_out=32, ctr_final=4
// ws layout (floats): A[8*8*2048] | B[8*8*2048]  (B has SCALING folded in)

#define BS 8
#define SEQ 2048
#define DIM 2048
#define RR 8
#define SCALING 2.0f   // 16.0 / R

typedef float vf4 __attribute__((ext_vector_type(4)));

// ---------------------------------------------------------------------------
// Kernel 1: gating MLP (recomputed per block, cheap) + A/B generation.
// (unchanged from previous round — not on the critical path)
// ---------------------------------------------------------------------------
__global__ void gate_ab_kernel(const float* __restrict__ ctr,
                               const float* __restrict__ gamma,
                               const float* __restrict__ beta,
                               const float* __restrict__ W1,
                               const float* __restrict__ b1,
                               const float* __restrict__ W2,
                               const float* __restrict__ b2,
                               const float* __restrict__ Wa,
                               const float* __restrict__ Wb,
                               float* __restrict__ A,
                               float* __restrict__ B) {
    __shared__ float z_s[BS][32];
    __shared__ float h_s[BS][60];
    __shared__ float logit_s[BS][4];
    __shared__ float gate_s[BS][4];
    const int tid = threadIdx.x;

    {
        const int b = tid >> 5, i = tid & 31;
        float v = ctr[b * 32 + i];
        float s = v;
        #pragma unroll
        for (int m = 16; m; m >>= 1) s += __shfl_xor(s, m, 64);
        const float mu = s * (1.0f / 32.0f);
        const float d = v - mu;
        float sq = d * d;
        #pragma unroll
        for (int m = 16; m; m >>= 1) sq += __shfl_xor(sq, m, 64);
        const float var = sq * (1.0f / 32.0f);
        z_s[b][i] = d * rsqrtf(var + 1e-5f) * gamma[i] + beta[i];
    }
    __syncthreads();

    for (int idx = tid; idx < BS * 60; idx += 256) {
        const int b = idx / 60, j = idx % 60;
        float acc = b1[j];
        #pragma unroll
        for (int k = 0; k < 32; ++k) acc += z_s[b][k] * W1[j * 32 + k];
        h_s[b][j] = fmaxf(acc, 0.0f);
    }
    __syncthreads();

    if (tid < 32) {
        const int b = tid >> 2, c = tid & 3;
        float acc = b2[c];
        for (int k = 0; k < 60; ++k) acc += h_s[b][k] * W2[c * 60 + k];
        logit_s[b][c] = acc;
    }
    __syncthreads();

    if (tid < 8) {
        float m = logit_s[tid][0];
        #pragma unroll
        for (int c = 1; c < 4; ++c) m = fmaxf(m, logit_s[tid][c]);
        float e[4], s = 0.0f;
        #pragma unroll
        for (int c = 0; c < 4; ++c) { e[c] = expf(logit_s[tid][c] - m); s += e[c]; }
        const float inv = 1.0f / s;
        #pragma unroll
        for (int c = 0; c < 4; ++c) gate_s[tid][c] = e[c] * inv;
    }
    __syncthreads();

    const vf4* __restrict__ Wa4 = (const vf4*)Wa;
    const vf4* __restrict__ Wb4 = (const vf4*)Wb;
    const int total = BS * RR * DIM;   // 131072
    for (int idx = blockIdx.x * 256 + tid; idx < total; idx += gridDim.x * 256) {
        const int b = idx >> 14, rd = idx & 16383;
        const vf4 g = *(const vf4*)gate_s[b];
        const vf4 wa = Wa4[rd];
        A[idx] = g.x * wa.x + g.y * wa.y + g.z * wa.z + g.w * wa.w;
        const vf4 wb = Wb4[rd];
        B[idx] = SCALING * (g.x * wb.x + g.y * wb.y + g.z * wb.z + g.w * wb.w);
    }
}

// ---------------------------------------------------------------------------
// Fused kernel, v2: NO LDS, NO BARRIERS.
// Each 64-lane wave independently owns 4 seq rows:
//   phase 1: xa[i][r] = dot(x[row i], A[r])   (A read straight from L2/L3;
//            x loads pipelined 1 deep; butterfly reduce in-register)
//   phase 2: out[row i] = xa[i] . B           (B from L2/L3; non-temporal
//            stores so `out` doesn't evict x from the 256 MB L3)
// 256-thread blocks (4 waves, 16 rows), 1024 blocks, zero LDS.
// Waves free-run -> reads and writes from different waves interleave on the
// memory pipe instead of the old barrier-aligned read-burst/write-burst.
// ---------------------------------------------------------------------------
__global__ void __launch_bounds__(256, 4)
fused_kernel(const float* __restrict__ x, const float* __restrict__ A,
             const float* __restrict__ B, float* __restrict__ out) {
    const int b    = blockIdx.x >> 7;     // 128 blocks per sample
    const int tile = blockIdx.x & 127;    // 16 rows per block
    const int wave = threadIdx.x >> 6, lane = threadIdx.x & 63;

    const float* __restrict__ xr =
        x + ((size_t)(b * SEQ + tile * 16 + wave * 4)) * DIM;
    const float* __restrict__ Ab = A + b * (RR * DIM);

    float acc[4][8];
    #pragma unroll
    for (int i = 0; i < 4; ++i)
        #pragma unroll
        for (int r = 0; r < 8; ++r) acc[i][r] = 0.0f;

    // ---- phase 1: xa = x . A^T, x-loads pipelined 1 deep ----
    vf4 xcur[4], xnxt[4];
    {
        const int d0 = lane * 4;
        #pragma unroll
        for (int i = 0; i < 4; ++i)
            xcur[i] = *(const vf4*)&xr[(size_t)i * DIM + d0];
    }
    #pragma unroll
    for (int j = 0; j < 8; ++j) {
        const int d = j * 256 + lane * 4;
        if (j < 7) {
            #pragma unroll
            for (int i = 0; i < 4; ++i)
                xnxt[i] = *(const vf4*)&xr[(size_t)i * DIM + d + 256];
        }
        vf4 a4[8];
        #pragma unroll
        for (int r = 0; r < 8; ++r) a4[r] = *(const vf4*)&Ab[r * DIM + d];
        #pragma unroll
        for (int i = 0; i < 4; ++i) {
            #pragma unroll
            for (int r = 0; r < 8; ++r)
                acc[i][r] += xcur[i].x * a4[r].x + xcur[i].y * a4[r].y +
                             xcur[i].z * a4[r].z + xcur[i].w * a4[r].w;
        }
        #pragma unroll
        for (int i = 0; i < 4; ++i) xcur[i] = xnxt[i];
    }

    // butterfly reduce across 64 lanes -> every lane holds xa[i][r]
    float xa[4][8];
    #pragma unroll
    for (int i = 0; i < 4; ++i) {
        #pragma unroll
        for (int r = 0; r < 8; ++r) {
            float v = acc[i][r];
            #pragma unroll
            for (int off = 32; off; off >>= 1) v += __shfl_xor(v, off, 64);
            xa[i][r] = v;
        }
    }

    // ---- phase 2: out = xa . B, B straight from cache, NT stores ----
    const float* __restrict__ Bb = B + b * (RR * DIM);
    float* __restrict__ ob =
        out + ((size_t)(b * SEQ + tile * 16 + wave * 4)) * DIM;
    #pragma unroll
    for (int j = 0; j < 8; ++j) {
        const int o = j * 256 + lane * 4;
        vf4 b4[8];
        #pragma unroll
        for (int r = 0; r < 8; ++r) b4[r] = *(const vf4*)&Bb[r * DIM + o];
        #pragma unroll
        for (int i = 0; i < 4; ++i) {
            vf4 v = {0.0f, 0.0f, 0.0f, 0.0f};
            #pragma unroll
            for (int r = 0; r < 8; ++r) {
                v.x += xa[i][r] * b4[r].x;
                v.y += xa[i][r] * b4[r].y;
                v.z += xa[i][r] * b4[r].z;
                v.w += xa[i][r] * b4[r].w;
            }
            __builtin_nontemporal_store(v, (vf4*)&ob[(size_t)i * DIM + o]);
        }
    }
}

extern "C" void kernel_launch(void* const* d_in, const int* in_sizes, int n_in,
                              void* d_out, int out_size, void* d_ws, size_t ws_size,
                              hipStream_t stream) {
    const float* x     = (const float*)d_in[0];
    const float* ctr   = (const float*)d_in[1];
    const float* gamma = (const float*)d_in[2];
    const float* beta  = (const float*)d_in[3];
    const float* W1    = (const float*)d_in[4];
    const float* b1    = (const float*)d_in[5];
    const float* W2    = (const float*)d_in[6];
    const float* b2    = (const float*)d_in[7];
    const float* Wa    = (const float*)d_in[8];
    const float* Wb    = (const float*)d_in[9];

    float* ws = (float*)d_ws;
    float* A  = ws;                  // 131072 floats
    float* B  = ws + 131072;         // 131072 floats
    float* out = (float*)d_out;

    gate_ab_kernel<<<128, 256, 0, stream>>>(ctr, gamma, beta, W1, b1, W2, b2,
                                            Wa, Wb, A, B);
    fused_kernel<<<BS * SEQ / 16, 256, 0, stream>>>(x, A, B, out);
}

// Round 3
// 279.093 us; speedup vs baseline: 1.6616x; 1.6616x over previous
//
#include <hip/hip_runtime.h>
#include <math.h>

// Problem: bs=8, seq=2048, d_in=d_out=2048, R=8, ctr_out=32, ctr_final=4
// ws layout (floats): A[8*8*2048] | B[8*8*2048] | xa[8*2048*8]
// (B has SCALING folded in)

#define BS 8
#define SEQ 2048
#define DIM 2048
#define RR 8
#define SCALING 2.0f   // 16.0 / R

typedef float vf4 __attribute__((ext_vector_type(4)));

// ---------------------------------------------------------------------------
// Kernel 1: gating MLP + A/B generation. (unchanged — ~6 µs, off critical path)
// ---------------------------------------------------------------------------
__global__ void gate_ab_kernel(const float* __restrict__ ctr,
                               const float* __restrict__ gamma,
                               const float* __restrict__ beta,
                               const float* __restrict__ W1,
                               const float* __restrict__ b1,
                               const float* __restrict__ W2,
                               const float* __restrict__ b2,
                               const float* __restrict__ Wa,
                               const float* __restrict__ Wb,
                               float* __restrict__ A,
                               float* __restrict__ B) {
    __shared__ float z_s[BS][32];
    __shared__ float h_s[BS][60];
    __shared__ float logit_s[BS][4];
    __shared__ float gate_s[BS][4];
    const int tid = threadIdx.x;

    {
        const int b = tid >> 5, i = tid & 31;
        float v = ctr[b * 32 + i];
        float s = v;
        #pragma unroll
        for (int m = 16; m; m >>= 1) s += __shfl_xor(s, m, 64);
        const float mu = s * (1.0f / 32.0f);
        const float d = v - mu;
        float sq = d * d;
        #pragma unroll
        for (int m = 16; m; m >>= 1) sq += __shfl_xor(sq, m, 64);
        const float var = sq * (1.0f / 32.0f);
        z_s[b][i] = d * rsqrtf(var + 1e-5f) * gamma[i] + beta[i];
    }
    __syncthreads();

    for (int idx = tid; idx < BS * 60; idx += 256) {
        const int b = idx / 60, j = idx % 60;
        float acc = b1[j];
        #pragma unroll
        for (int k = 0; k < 32; ++k) acc += z_s[b][k] * W1[j * 32 + k];
        h_s[b][j] = fmaxf(acc, 0.0f);
    }
    __syncthreads();

    if (tid < 32) {
        const int b = tid >> 2, c = tid & 3;
        float acc = b2[c];
        for (int k = 0; k < 60; ++k) acc += h_s[b][k] * W2[c * 60 + k];
        logit_s[b][c] = acc;
    }
    __syncthreads();

    if (tid < 8) {
        float m = logit_s[tid][0];
        #pragma unroll
        for (int c = 1; c < 4; ++c) m = fmaxf(m, logit_s[tid][c]);
        float e[4], s = 0.0f;
        #pragma unroll
        for (int c = 0; c < 4; ++c) { e[c] = expf(logit_s[tid][c] - m); s += e[c]; }
        const float inv = 1.0f / s;
        #pragma unroll
        for (int c = 0; c < 4; ++c) gate_s[tid][c] = e[c] * inv;
    }
    __syncthreads();

    const vf4* __restrict__ Wa4 = (const vf4*)Wa;
    const vf4* __restrict__ Wb4 = (const vf4*)Wb;
    const int total = BS * RR * DIM;   // 131072
    for (int idx = blockIdx.x * 256 + tid; idx < total; idx += gridDim.x * 256) {
        const int b = idx >> 14, rd = idx & 16383;
        const vf4 g = *(const vf4*)gate_s[b];
        const vf4 wa = Wa4[rd];
        A[idx] = g.x * wa.x + g.y * wa.y + g.z * wa.z + g.w * wa.w;
        const vf4 wb = Wb4[rd];
        B[idx] = SCALING * (g.x * wb.x + g.y * wb.y + g.z * wb.z + g.w * wb.w);
    }
}

// ---------------------------------------------------------------------------
// Kernel 2: xa = x . A^T  — pure READ stream.
// No LDS, no barriers. Each wave owns 4 seq rows; A[b] (64 KB) read straight
// from L2; x pipelined 1 deep from HBM. Butterfly-reduce, lanes 0-31 write
// the 32 xa values (contiguous 128 B per wave).
// ---------------------------------------------------------------------------
__global__ void __launch_bounds__(256, 4)
xa_kernel(const float* __restrict__ x, const float* __restrict__ A,
          float* __restrict__ xa) {
    const int b    = blockIdx.x >> 7;     // 128 blocks per sample
    const int tile = blockIdx.x & 127;    // 16 rows per block
    const int wave = threadIdx.x >> 6, lane = threadIdx.x & 63;
    const int row0 = tile * 16 + wave * 4;

    const float* __restrict__ xr = x + ((size_t)(b * SEQ + row0)) * DIM;
    const float* __restrict__ Ab = A + b * (RR * DIM);

    float acc[4][8];
    #pragma unroll
    for (int i = 0; i < 4; ++i)
        #pragma unroll
        for (int r = 0; r < 8; ++r) acc[i][r] = 0.0f;

    vf4 xcur[4], xnxt[4];
    {
        const int d0 = lane * 4;
        #pragma unroll
        for (int i = 0; i < 4; ++i)
            xcur[i] = *(const vf4*)&xr[(size_t)i * DIM + d0];
    }
    #pragma unroll
    for (int j = 0; j < 8; ++j) {
        const int d = j * 256 + lane * 4;
        if (j < 7) {
            #pragma unroll
            for (int i = 0; i < 4; ++i)
                xnxt[i] = *(const vf4*)&xr[(size_t)i * DIM + d + 256];
        }
        vf4 a4[8];
        #pragma unroll
        for (int r = 0; r < 8; ++r) a4[r] = *(const vf4*)&Ab[r * DIM + d];
        #pragma unroll
        for (int i = 0; i < 4; ++i) {
            #pragma unroll
            for (int r = 0; r < 8; ++r)
                acc[i][r] += xcur[i].x * a4[r].x + xcur[i].y * a4[r].y +
                             xcur[i].z * a4[r].z + xcur[i].w * a4[r].w;
        }
        #pragma unroll
        for (int i = 0; i < 4; ++i) xcur[i] = xnxt[i];
    }

    // butterfly reduce across 64 lanes -> every lane holds all xa[i][r]
    float xv[4][8];
    #pragma unroll
    for (int i = 0; i < 4; ++i) {
        #pragma unroll
        for (int r = 0; r < 8; ++r) {
            float v = acc[i][r];
            #pragma unroll
            for (int off = 32; off; off >>= 1) v += __shfl_xor(v, off, 64);
            xv[i][r] = v;
        }
    }

    // lanes 0..31 write xa: lane = i*8 + r -> contiguous 32 floats per wave.
    // Static selection (cndmask chain) — NO runtime register indexing.
    if (lane < 32) {
        float v = 0.0f;
        #pragma unroll
        for (int i = 0; i < 4; ++i)
            #pragma unroll
            for (int r = 0; r < 8; ++r)
                if (lane == i * 8 + r) v = xv[i][r];
        xa[((size_t)(b * SEQ + row0)) * RR + lane] = v;
    }
}

// ---------------------------------------------------------------------------
// Kernel 3: out = xa . B — pure WRITE stream.
// No LDS, no barriers. xa (512 KB) and B[b] (64 KB) are L2-resident; out is
// written with plain float4 stores (NT stores scalarize -> 4x write amp,
// measured round 1 — do not reintroduce).
// ---------------------------------------------------------------------------
__global__ void __launch_bounds__(256, 4)
out_kernel(const float* __restrict__ xa, const float* __restrict__ B,
           float* __restrict__ out) {
    const int b    = blockIdx.x >> 7;
    const int tile = blockIdx.x & 127;
    const int wave = threadIdx.x >> 6, lane = threadIdx.x & 63;
    const int row0 = tile * 16 + wave * 4;

    const float* __restrict__ Bb = B + b * (RR * DIM);
    float* __restrict__ ob = out + ((size_t)(b * SEQ + row0)) * DIM;

    // xa for this wave's 4 rows (uniform across lanes, L2/L1-broadcast)
    float xv[4][8];
    #pragma unroll
    for (int i = 0; i < 4; ++i) {
        const vf4 lo = *(const vf4*)&xa[((size_t)(b * SEQ + row0 + i)) * RR];
        const vf4 hi = *(const vf4*)&xa[((size_t)(b * SEQ + row0 + i)) * RR + 4];
        xv[i][0] = lo.x; xv[i][1] = lo.y; xv[i][2] = lo.z; xv[i][3] = lo.w;
        xv[i][4] = hi.x; xv[i][5] = hi.y; xv[i][6] = hi.z; xv[i][7] = hi.w;
    }

    #pragma unroll
    for (int j = 0; j < 8; ++j) {
        const int o = j * 256 + lane * 4;
        vf4 b4[8];
        #pragma unroll
        for (int r = 0; r < 8; ++r) b4[r] = *(const vf4*)&Bb[r * DIM + o];
        #pragma unroll
        for (int i = 0; i < 4; ++i) {
            vf4 v = {0.0f, 0.0f, 0.0f, 0.0f};
            #pragma unroll
            for (int r = 0; r < 8; ++r) {
                v.x += xv[i][r] * b4[r].x;
                v.y += xv[i][r] * b4[r].y;
                v.z += xv[i][r] * b4[r].z;
                v.w += xv[i][r] * b4[r].w;
            }
            *(vf4*)&ob[(size_t)i * DIM + o] = v;
        }
    }
}

extern "C" void kernel_launch(void* const* d_in, const int* in_sizes, int n_in,
                              void* d_out, int out_size, void* d_ws, size_t ws_size,
                              hipStream_t stream) {
    const float* x     = (const float*)d_in[0];
    const float* ctr   = (const float*)d_in[1];
    const float* gamma = (const float*)d_in[2];
    const float* beta  = (const float*)d_in[3];
    const float* W1    = (const float*)d_in[4];
    const float* b1    = (const float*)d_in[5];
    const float* W2    = (const float*)d_in[6];
    const float* b2    = (const float*)d_in[7];
    const float* Wa    = (const float*)d_in[8];
    const float* Wb    = (const float*)d_in[9];

    float* ws = (float*)d_ws;
    float* A  = ws;                  // 131072 floats
    float* B  = ws + 131072;         // 131072 floats
    float* xa = ws + 262144;         // 131072 floats (8*2048*8)
    float* out = (float*)d_out;

    gate_ab_kernel<<<128, 256, 0, stream>>>(ctr, gamma, beta, W1, b1, W2, b2,
                                            Wa, Wb, A, B);
    xa_kernel<<<BS * SEQ / 16, 256, 0, stream>>>(x, A, xa);
    out_kernel<<<BS * SEQ / 16, 256, 0, stream>>>(xa, B, out);
}